// Round 2
// baseline (6258.322 us; speedup 1.0000x reference)
//
#include <hip/hip_runtime.h>
#include <stdint.h>

#define TT 512
#define BB 64
#define II 512
#define HH 512
#define GG 2048   // 4H
#define KK 1024   // I + H

typedef short short8 __attribute__((ext_vector_type(8)));
typedef float floatx4 __attribute__((ext_vector_type(4)));

// workspace layout
static constexpr size_t WX_BYTES   = (size_t)2 * GG * II * 2;       // 4 MB bf16 [dir][2048][512]  x-part weights
static constexpr size_t WH_BYTES   = (size_t)2 * 32 * 32768 * 2;    // 4 MB bf16 [dir][slice][32768] h-part frag images
static constexpr size_t XB_BYTES   = (size_t)TT * BB * II * 2;      // 32 MB bf16 [T][B][I]
static constexpr size_t FLAG_INTS  = (size_t)2 * TT * 32 * 32;      // 4 MB: flags[dir][t][blk] 128B lines; +wid*8 sub-slot
static constexpr size_t FLAG_BYTES = FLAG_INTS * 4;
static constexpr size_t HX_BYTES   = (size_t)2 * TT * BB * HH * 2;  // 64 MB bf16 [dir][t][B][H] h-exchange
static constexpr size_t XP_BYTES   = (size_t)2 * TT * GG * BB * 4;  // 512 MB fp32 [dir][t][n][b] x-projection

__device__ __forceinline__ unsigned short f2bf(float f) {
  unsigned int u = __float_as_uint(f);
  unsigned int r = (u + 0x7fffu + ((u >> 16) & 1u)) >> 16;   // round-to-nearest-even
  return (unsigned short)r;
}

// L2-scope (same-XCD) ops: bypass L1 (sc0), hit the shared per-XCD L2.
__device__ __forceinline__ unsigned int ld_sc0(const int* p) {
  unsigned int v;
  asm volatile("global_load_dword %0, %1, off sc0\n\ts_waitcnt vmcnt(0)"
               : "=v"(v) : "v"(p) : "memory");
  return v;
}
__device__ __forceinline__ void st_sc0(unsigned int* p, unsigned int v) {
  asm volatile("global_store_dword %0, %1, off sc0" :: "v"(p), "v"(v) : "memory");
}

// ---- prep: weights -> wx (x-part, [dir][n][k<512]) + wh (h-part frag image); zero flags
__global__ void prep_kernel(const float* __restrict__ Wih_f, const float* __restrict__ Whh_f,
                            const float* __restrict__ Wih_b, const float* __restrict__ Whh_b,
                            unsigned short* __restrict__ wx,
                            unsigned short* __restrict__ wh,
                            int* __restrict__ flags)
{
  size_t tid0 = (size_t)blockIdx.x * blockDim.x + threadIdx.x;
  size_t stride = (size_t)gridDim.x * blockDim.x;

  const size_t WC = (size_t)2 * GG * KK;   // 2^22
  for (size_t idx = tid0; idx < WC; idx += stride) {
    int dir = (int)(idx >> 21);
    int rem = (int)(idx & ((1u << 21) - 1));
    int n = rem >> 10;        // 0..2047
    int k = rem & 1023;       // 0..1023
    if (k < II) {
      const float* Wih = dir ? Wih_b : Wih_f;
      wx[(size_t)dir * GG * II + (size_t)n * II + k] = f2bf(Wih[(size_t)n * II + k]);
    } else {
      const float* Whh = dir ? Whh_b : Whh_f;
      int kk = k - II;            // 0..511
      int kc = kk >> 5;           // 0..15
      int r  = kk & 31;
      int quad = r >> 3;          // 0..3
      int e  = r & 7;             // 0..7
      int g   = n >> 9;           // 0..3
      int blk = (n >> 4) & 31;    // col-16-slice 0..31
      int j   = n & 15;           // 0..15
      size_t lidx = ((size_t)((g * 16 + kc) * 4 + quad) * 16 + j) * 8 + e;
      wh[((size_t)dir * 32 + blk) * 32768 + lidx] = f2bf(Whh[(size_t)n * HH + kk]);
    }
  }

  for (size_t idx = tid0; idx < FLAG_INTS; idx += stride) flags[idx] = 0;
}

// ---- x -> bf16
__global__ void xconv_kernel(const float* __restrict__ x, unsigned short* __restrict__ xb) {
  size_t i = (size_t)blockIdx.x * blockDim.x + threadIdx.x;
  size_t stride = (size_t)gridDim.x * blockDim.x;
  const size_t n4 = (size_t)TT * BB * II / 4;
  const float4* xp = (const float4*)x;
  ushort4* op = (ushort4*)xb;
  for (; i < n4; i += stride) {
    float4 v = xp[i];
    ushort4 o;
    o.x = f2bf(v.x); o.y = f2bf(v.y); o.z = f2bf(v.z); o.w = f2bf(v.w);
    op[i] = o;
  }
}

// ---- x_proj GEMM: xp[dir][t][n][b] = sum_k xb[t][b][k] * wx[dir][n][k]
// Same MFMA/frag pattern and accumulation order as the in-loop x-part => bit-identical.
__global__ __launch_bounds__(256) void xproj_kernel(const unsigned short* __restrict__ xb,
                                                    const unsigned short* __restrict__ wx,
                                                    float* __restrict__ xp)
{
  const int bid = blockIdx.x;            // 2 * 512 * 32 = 32768 blocks
  const int dir = bid >> 14;
  const int rem = bid & 16383;
  const int t   = rem >> 5;              // 0..511
  const int n0  = (rem & 31) << 6;       // 0..2047 step 64
  const int tid  = threadIdx.x;
  const int lane = tid & 63;
  const int l15  = lane & 15;
  const int quad = lane >> 4;
  const int m0   = (tid >> 6) << 4;      // wave -> 16 batch rows

  const unsigned short* arow = xb + ((size_t)t * BB + m0 + l15) * II + quad * 8;
  const unsigned short* wxr[4];
#pragma unroll
  for (int ns = 0; ns < 4; ++ns)
    wxr[ns] = wx + (size_t)dir * GG * II + (size_t)(n0 + ns * 16 + l15) * II + quad * 8;

  floatx4 acc[4];
#pragma unroll
  for (int ns = 0; ns < 4; ++ns) acc[ns] = (floatx4){0.f, 0.f, 0.f, 0.f};

#pragma unroll
  for (int kc = 0; kc < 16; ++kc) {
    short8 a = *(const short8*)(arow + kc * 32);
#pragma unroll
    for (int ns = 0; ns < 4; ++ns) {
      short8 b = *(const short8*)(wxr[ns] + kc * 32);
      acc[ns] = __builtin_amdgcn_mfma_f32_16x16x32_bf16(a, b, acc[ns], 0, 0, 0);
    }
  }

#pragma unroll
  for (int ns = 0; ns < 4; ++ns) {
    float* crow = xp + (((size_t)dir * TT + t) * GG + (size_t)(n0 + ns * 16 + l15)) * BB
                     + m0 + quad * 4;
    *(floatx4*)crow = acc[ns];
  }
}

// ---- persistent bidirectional LSTM, round 6
// grid = 256 blocks; only bid%8 in {0,1} participate (dir = bid%8, blk = bid>>3).
// Under the empirical round-robin dispatch (bid%8 -> XCD), each dir's 32 blocks
// land on ONE XCD (32 CUs) => all h/flag exchange through the shared per-XCD L2
// (sc0 ops, ~200cy) instead of MALL agent-scope (~1us hops). Co-location is
// VERIFIED at runtime via HW_REG_XCC_ID agreement (plus cross-dir inequality);
// on failure falls back to the round-5 agent-scope protocol. Fast-path flags
// are dual-published (sc0 + agent) so a wrong fast decision cannot deadlock.
// XPROJ: x-part precomputed by xproj_kernel; the step's x-contribution is 4
// float4 loads instead of ~80 L2 loads + 64 MFMAs.
template<bool XPROJ>
__global__ __launch_bounds__(256, 1) void lstm_kernel(
    const unsigned short* __restrict__ xb,
    const unsigned short* __restrict__ wx,
    const unsigned short* __restrict__ wh,
    int* __restrict__ flags,
    const float* __restrict__ h0,
    const float* __restrict__ c0,
    const float* __restrict__ b_f,
    const float* __restrict__ b_b,
    float* __restrict__ out,
    unsigned short* __restrict__ hx,
    const float* __restrict__ xp)
{
  const int bid  = blockIdx.x;
  if ((bid & 7) > 1) return;             // 192 idle blocks exit
  const int dir  = bid & 7;              // 0 or 1
  const int blk  = bid >> 3;             // 0..31
  const int j0   = blk << 4;
  const int tid  = threadIdx.x;
  const int lane = tid & 63;
  const int l15  = lane & 15;
  const int quad = lane >> 4;
  const int wid  = tid >> 6;
  const int m0   = wid << 4;

  int* fl_dir = flags + (size_t)dir * TT * 1024;

  // ---- runtime co-location check ----
  unsigned xcc = 0;
  asm volatile("s_getreg_b32 %0, hwreg(HW_REG_XCC_ID)" : "=s"(xcc));
  if (tid == 0)
    __hip_atomic_store(fl_dir + blk * 32 + 4, (int)xcc + 1,
                       __ATOMIC_RELAXED, __HIP_MEMORY_SCOPE_AGENT);
  int dv = 1;
  while (true) {
    if (lane < 32)
      dv = __hip_atomic_load(fl_dir + lane * 32 + 4,
                             __ATOMIC_RELAXED, __HIP_MEMORY_SCOPE_AGENT);
    else if (lane == 32)
      dv = __hip_atomic_load(flags + (size_t)(1 - dir) * TT * 1024 + 4,
                             __ATOMIC_RELAXED, __HIP_MEMORY_SCOPE_AGENT);
    if (__ballot(dv != 0) == ~0ull) break;
    __builtin_amdgcn_s_sleep(8);
  }
  const int v0 = __shfl(dv, 0);
  const int vo = __shfl(dv, 32);
  const bool fast =
      (__ballot(lane < 32 ? (dv == v0) : 1) == ~0ull) && (v0 != vo);

  // ---- h-part weights resident in VGPRs: frag (g,kc) at wb[g*16+kc] ----
  short8 wb[64];
  {
    const unsigned short* wsrc = wh + ((size_t)dir * 32 + blk) * 32768
                                    + (size_t)(quad * 16 + l15) * 8;
#pragma unroll
    for (int f = 0; f < 64; ++f)
      wb[f] = *(const short8*)(wsrc + (size_t)f * 512);
  }

  const float* bias = dir ? b_b : b_f;
  float bs[4];
#pragma unroll
  for (int g = 0; g < 4; ++g) bs[g] = bias[g * HH + j0 + l15];

  float cst[4];
#pragma unroll
  for (int r = 0; r < 4; ++r)
    cst[r] = c0[(size_t)dir * BB * HH + (size_t)(m0 + quad * 4 + r) * HH + j0 + l15];

  // x-part B row pointers (only used when !XPROJ)
  const unsigned short* wxrow[4];
#pragma unroll
  for (int g = 0; g < 4; ++g)
    wxrow[g] = wx + (size_t)dir * GG * II + (size_t)(g * HH + j0 + l15) * II + quad * 8;

  for (int t = 0; t < TT; ++t) {
    const int tt2 = dir ? (TT - 1 - t) : t;

    floatx4 acc[4];
    if (XPROJ) {
      const float* xrow = xp + (((size_t)dir * TT + tt2) * GG + (size_t)(j0 + l15)) * BB
                             + m0 + quad * 4;
#pragma unroll
      for (int g = 0; g < 4; ++g)
        acc[g] = *(const floatx4*)(xrow + (size_t)g * HH * BB);
    } else {
#pragma unroll
      for (int g = 0; g < 4; ++g) acc[g] = (floatx4){0.f, 0.f, 0.f, 0.f};
      const unsigned short* arow = xb + (size_t)tt2 * BB * II + (size_t)(m0 + l15) * II + quad * 8;
#pragma unroll
      for (int kc = 0; kc < 16; ++kc) {
        short8 a = *(const short8*)(arow + kc * 32);
#pragma unroll
        for (int g = 0; g < 4; ++g) {
          short8 b = *(const short8*)(wxrow[g] + kc * 32);
          acc[g] = __builtin_amdgcn_mfma_f32_16x16x32_bf16(a, b, acc[g], 0, 0, 0);
        }
      }
    }

    // ---- wait for h_{t-1}: per-wave poll, no barrier ----
    if (t > 0) {
      int* fl = fl_dir + (((size_t)(t - 1) << 5) + (lane & 31)) * 32 + wid * 8;
      int vv = 1, spin = 0;
      while (true) {
        if (lane < 32) {
          if (fast)
            vv = (spin < 4096)
               ? (int)ld_sc0(fl)
               : __hip_atomic_load(fl + 1, __ATOMIC_RELAXED, __HIP_MEMORY_SCOPE_AGENT);
          else
            vv = (spin < 32)
               ? __hip_atomic_load(fl, __ATOMIC_RELAXED, __HIP_MEMORY_SCOPE_AGENT)
               : __hip_atomic_fetch_add(fl, 0, __ATOMIC_RELAXED, __HIP_MEMORY_SCOPE_AGENT);
        }
        if (__ballot(vv > 0) == ~0ull) break;
        ++spin;
        __builtin_amdgcn_s_sleep(1);
      }
      asm volatile("" ::: "memory");   // keep h loads below the wait
    }

    // ---- h contribution (k = 512..1023), B from VGPRs ----
    if (t > 0) {
      const unsigned short* hrow = hx + (((size_t)dir * TT + (t - 1)) * BB + (size_t)(m0 + l15)) * HH + quad * 8;
#pragma unroll
      for (int kc = 0; kc < 16; ++kc) {
        short8 a = *(const short8*)(hrow + kc * 32);
#pragma unroll
        for (int g = 0; g < 4; ++g)
          acc[g] = __builtin_amdgcn_mfma_f32_16x16x32_bf16(a, wb[g * 16 + kc], acc[g], 0, 0, 0);
      }
    } else {
      const float* hrow = h0 + (size_t)dir * BB * HH + (size_t)(m0 + l15) * HH + quad * 8;
#pragma unroll
      for (int kc = 0; kc < 16; ++kc) {
        float4 v0f = *(const float4*)(hrow + (size_t)kc * 32);
        float4 v1f = *(const float4*)(hrow + (size_t)kc * 32 + 4);
        short8 a;
        a[0] = (short)f2bf(v0f.x); a[1] = (short)f2bf(v0f.y);
        a[2] = (short)f2bf(v0f.z); a[3] = (short)f2bf(v0f.w);
        a[4] = (short)f2bf(v1f.x); a[5] = (short)f2bf(v1f.y);
        a[6] = (short)f2bf(v1f.z); a[7] = (short)f2bf(v1f.w);
#pragma unroll
        for (int g = 0; g < 4; ++g)
          acc[g] = __builtin_amdgcn_mfma_f32_16x16x32_bf16(a, wb[g * 16 + kc], acc[g], 0, 0, 0);
      }
    }

    // ---- gates + state update ----
    float hf[4];
#pragma unroll
    for (int r = 0; r < 4; ++r) {
      float gi = acc[0][r] + bs[0];
      float gf = acc[1][r] + bs[1];
      float gg = acc[2][r] + bs[2];
      float go = acc[3][r] + bs[3];
      float si = 1.f / (1.f + __expf(-gi));
      float sf = 1.f / (1.f + __expf(-gf));
      float tg = 2.f / (1.f + __expf(-2.f * gg)) - 1.f;
      float so = 1.f / (1.f + __expf(-go));
      float c  = sf * cst[r] + si * tg;
      cst[r] = c;
      float th = 2.f / (1.f + __expf(-2.f * c)) - 1.f;
      hf[r] = so * th;
    }

    // ---- publish bf16 h: pack column pairs into dwords ----
    unsigned int pk[4];
#pragma unroll
    for (int r = 0; r < 4; ++r) {
      unsigned int mine  = f2bf(hf[r]);
      unsigned int other = (unsigned int)(unsigned short)__shfl_xor((int)mine, 1);
      pk[r] = (l15 & 1) ? (other | (mine << 16)) : (mine | (other << 16));
    }
    unsigned short* hxt = hx + ((size_t)dir * TT + t) * BB * HH + (j0 + (l15 & ~1));
    const int rb = (l15 & 1) << 1;
#pragma unroll
    for (int rr = 0; rr < 2; ++rr) {
      int row = m0 + quad * 4 + rb + rr;
      unsigned int* addr = (unsigned int*)(hxt + (size_t)row * HH);
      if (fast) st_sc0(addr, pk[rb + rr]);
      else __hip_atomic_store(addr, pk[rb + rr],
                              __ATOMIC_RELAXED, __HIP_MEMORY_SCOPE_AGENT);
    }
    asm volatile("s_waitcnt vmcnt(0)" ::: "memory");   // h stores visible (L2 fast / MALL slow)
    if (lane == 0) {
      int* flp = fl_dir + (((size_t)t << 5) + blk) * 32 + wid * 8;
      if (fast) {
        st_sc0((unsigned int*)flp, 1u);
        __hip_atomic_store(flp + 1, 1, __ATOMIC_RELAXED, __HIP_MEMORY_SCOPE_AGENT);
      } else {
        __hip_atomic_store(flp, 1, __ATOMIC_RELAXED, __HIP_MEMORY_SCOPE_AGENT);
      }
    }

    // fp32 output (cached, off critical path, flushed at kernel end)
    float* orow = out + (size_t)tt2 * BB * 2 * HH + (size_t)dir * HH + j0 + l15;
#pragma unroll
    for (int r = 0; r < 4; ++r)
      orow[(size_t)(m0 + quad * 4 + r) * 2 * HH] = hf[r];
  }
}

// ---- minimal legacy fallback (tiny workspace): fp32 x, exchange fp32 h via out
__global__ __launch_bounds__(256, 1) void lstm_legacy(
    const float* __restrict__ x_f32,
    const unsigned short* __restrict__ wx,
    const unsigned short* __restrict__ wh,
    int* __restrict__ flags,
    const float* __restrict__ h0,
    const float* __restrict__ c0,
    const float* __restrict__ b_f,
    const float* __restrict__ b_b,
    float* __restrict__ out)
{
  const int bid  = blockIdx.x;
  const int dir  = bid >> 5;
  const int blk  = bid & 31;
  const int j0   = blk << 4;
  const int tid  = threadIdx.x;
  const int lane = tid & 63;
  const int l15  = lane & 15;
  const int quad = lane >> 4;
  const int wid  = tid >> 6;
  const int m0   = wid << 4;

  short8 wb[64];
  {
    const unsigned short* wsrc = wh + ((size_t)dir * 32 + blk) * 32768
                                    + (size_t)(quad * 16 + l15) * 8;
#pragma unroll
    for (int f = 0; f < 64; ++f)
      wb[f] = *(const short8*)(wsrc + (size_t)f * 512);
  }
  const float* bias = dir ? b_b : b_f;
  float bs[4];
#pragma unroll
  for (int g = 0; g < 4; ++g) bs[g] = bias[g * HH + j0 + l15];
  float cst[4];
#pragma unroll
  for (int r = 0; r < 4; ++r)
    cst[r] = c0[(size_t)dir * BB * HH + (size_t)(m0 + quad * 4 + r) * HH + j0 + l15];
  const unsigned short* wxrow[4];
#pragma unroll
  for (int g = 0; g < 4; ++g)
    wxrow[g] = wx + (size_t)dir * GG * II + (size_t)(g * HH + j0 + l15) * II + quad * 8;
  int* fl_dir = flags + (size_t)dir * TT * 1024;

  for (int t = 0; t < TT; ++t) {
    const int tt2 = dir ? (TT - 1 - t) : t;
    floatx4 acc[4];
#pragma unroll
    for (int g = 0; g < 4; ++g) acc[g] = (floatx4){0.f, 0.f, 0.f, 0.f};
    const float* arow = x_f32 + (size_t)tt2 * BB * II + (size_t)(m0 + l15) * II + quad * 8;
#pragma unroll
    for (int kc = 0; kc < 16; ++kc) {
      float4 v0 = *(const float4*)(arow + kc * 32);
      float4 v1 = *(const float4*)(arow + kc * 32 + 4);
      short8 a;
      a[0] = (short)f2bf(v0.x); a[1] = (short)f2bf(v0.y);
      a[2] = (short)f2bf(v0.z); a[3] = (short)f2bf(v0.w);
      a[4] = (short)f2bf(v1.x); a[5] = (short)f2bf(v1.y);
      a[6] = (short)f2bf(v1.z); a[7] = (short)f2bf(v1.w);
#pragma unroll
      for (int g = 0; g < 4; ++g) {
        short8 b = *(const short8*)(wxrow[g] + kc * 32);
        acc[g] = __builtin_amdgcn_mfma_f32_16x16x32_bf16(a, b, acc[g], 0, 0, 0);
      }
    }
    if (t > 0) {
      int* fl = fl_dir + (((size_t)(t - 1) << 5) + (lane & 31)) * 32 + wid * 8;
      int vv = 1, spin = 0;
      while (true) {
        if (lane < 32)
          vv = (spin < 32)
             ? __hip_atomic_load(fl, __ATOMIC_RELAXED, __HIP_MEMORY_SCOPE_AGENT)
             : __hip_atomic_fetch_add(fl, 0, __ATOMIC_RELAXED, __HIP_MEMORY_SCOPE_AGENT);
        if (__ballot(vv > 0) == ~0ull) break;
        ++spin;
        __builtin_amdgcn_s_sleep(1);
      }
      asm volatile("" ::: "memory");
    }
    const float* hrow;
    if (t == 0) hrow = h0 + (size_t)dir * BB * HH + (size_t)(m0 + l15) * HH + quad * 8;
    else {
      const int tp = dir ? (TT - t) : (t - 1);
      hrow = out + (size_t)tp * BB * 2 * HH + (size_t)(m0 + l15) * 2 * HH + (size_t)dir * HH + quad * 8;
    }
#pragma unroll
    for (int kc = 0; kc < 16; ++kc) {
      float4 v0 = *(const float4*)(hrow + (size_t)kc * 32);
      float4 v1 = *(const float4*)(hrow + (size_t)kc * 32 + 4);
      short8 a;
      a[0] = (short)f2bf(v0.x); a[1] = (short)f2bf(v0.y);
      a[2] = (short)f2bf(v0.z); a[3] = (short)f2bf(v0.w);
      a[4] = (short)f2bf(v1.x); a[5] = (short)f2bf(v1.y);
      a[6] = (short)f2bf(v1.z); a[7] = (short)f2bf(v1.w);
#pragma unroll
      for (int g = 0; g < 4; ++g)
        acc[g] = __builtin_amdgcn_mfma_f32_16x16x32_bf16(a, wb[g * 16 + kc], acc[g], 0, 0, 0);
    }
    float hf[4];
#pragma unroll
    for (int r = 0; r < 4; ++r) {
      float gi = acc[0][r] + bs[0];
      float gf = acc[1][r] + bs[1];
      float gg = acc[2][r] + bs[2];
      float go = acc[3][r] + bs[3];
      float si = 1.f / (1.f + __expf(-gi));
      float sf = 1.f / (1.f + __expf(-gf));
      float tg = 2.f / (1.f + __expf(-2.f * gg)) - 1.f;
      float so = 1.f / (1.f + __expf(-go));
      float c  = sf * cst[r] + si * tg;
      cst[r] = c;
      float th = 2.f / (1.f + __expf(-2.f * c)) - 1.f;
      hf[r] = so * th;
    }
    float* orow = out + (size_t)tt2 * BB * 2 * HH + (size_t)dir * HH + j0 + l15;
#pragma unroll
    for (int r = 0; r < 4; ++r)
      __hip_atomic_store(&orow[(size_t)(m0 + quad * 4 + r) * 2 * HH], hf[r],
                         __ATOMIC_RELAXED, __HIP_MEMORY_SCOPE_AGENT);
    asm volatile("s_waitcnt vmcnt(0)" ::: "memory");
    if (lane == 0)
      __hip_atomic_store(fl_dir + (((size_t)t << 5) + blk) * 32 + wid * 8, 1,
                         __ATOMIC_RELAXED, __HIP_MEMORY_SCOPE_AGENT);
  }
}

extern "C" void kernel_launch(void* const* d_in, const int* in_sizes, int n_in,
                              void* d_out, int out_size, void* d_ws, size_t ws_size,
                              hipStream_t stream)
{
  (void)in_sizes; (void)n_in; (void)out_size;
  const float* x     = (const float*)d_in[0];
  const float* h0    = (const float*)d_in[1];
  const float* c0    = (const float*)d_in[2];
  const float* Wih_f = (const float*)d_in[3];
  const float* Whh_f = (const float*)d_in[4];
  const float* b_f   = (const float*)d_in[5];
  const float* Wih_b = (const float*)d_in[6];
  const float* Whh_b = (const float*)d_in[7];
  const float* b_b   = (const float*)d_in[8];
  float* out = (float*)d_out;
  char* ws = (char*)d_ws;

  const size_t NEED_B = WX_BYTES + WH_BYTES + XB_BYTES + FLAG_BYTES + HX_BYTES;
  const size_t NEED_A = NEED_B + XP_BYTES;
  const bool modeA = ws_size >= NEED_A;
  const bool modeB = ws_size >= NEED_B;

  unsigned short* wx = (unsigned short*)ws;
  unsigned short* wh = (unsigned short*)(ws + WX_BYTES);
  unsigned short* xb = (unsigned short*)(ws + WX_BYTES + WH_BYTES);
  int* flags;
  unsigned short* hxp = nullptr;
  float* xpp = nullptr;
  if (modeB) {
    flags = (int*)(ws + WX_BYTES + WH_BYTES + XB_BYTES);
    hxp   = (unsigned short*)(ws + WX_BYTES + WH_BYTES + XB_BYTES + FLAG_BYTES);
    if (modeA) xpp = (float*)(ws + NEED_B);
  } else {
    flags = (int*)(ws + WX_BYTES + WH_BYTES);
  }

  prep_kernel<<<512, 256, 0, stream>>>(Wih_f, Whh_f, Wih_b, Whh_b, wx, wh, flags);
  if (modeA) {
    xconv_kernel<<<2048, 256, 0, stream>>>(x, xb);
    xproj_kernel<<<32768, 256, 0, stream>>>(xb, wx, xpp);
    lstm_kernel<true><<<256, 256, 0, stream>>>(xb, wx, wh, flags, h0, c0, b_f, b_b, out, hxp, xpp);
  } else if (modeB) {
    xconv_kernel<<<2048, 256, 0, stream>>>(x, xb);
    lstm_kernel<false><<<256, 256, 0, stream>>>(xb, wx, wh, flags, h0, c0, b_f, b_b, out, hxp, nullptr);
  } else {
    lstm_legacy<<<64, 256, 0, stream>>>(x, wx, wh, flags, h0, c0, b_f, b_b, out);
  }
}

// Round 3
// 5718.556 us; speedup vs baseline: 1.0944x; 1.0944x over previous
//
#include <hip/hip_runtime.h>
#include <stdint.h>

#define TT 512
#define BB 64
#define II 512
#define HH 512
#define GG 2048   // 4H
#define KK 1024   // I + H

typedef short short8 __attribute__((ext_vector_type(8)));
typedef float floatx4 __attribute__((ext_vector_type(4)));

// workspace layout
static constexpr size_t WX_BYTES   = (size_t)2 * GG * II * 2;       // 4 MB bf16 [dir][2048][512]  x-part weights
static constexpr size_t WH_BYTES   = (size_t)2 * 32 * 32768 * 2;    // 4 MB bf16 [dir][slice][32768] h-part frag images
static constexpr size_t XB_BYTES   = (size_t)TT * BB * II * 2;      // 32 MB bf16 [T][B][I]
static constexpr size_t FLAG_INTS  = (size_t)2 * TT * 32 * 32;      // 4 MB: flags[dir][t][blk] 128B lines; wid*8 sub-slot
static constexpr size_t FLAG_BYTES = FLAG_INTS * 4;
static constexpr size_t HX_BYTES   = (size_t)2 * TT * BB * HH * 2;  // 64 MB bf16 [dir][t][B][H] h-exchange

__device__ __forceinline__ unsigned short f2bf(float f) {
  unsigned int u = __float_as_uint(f);
  unsigned int r = (u + 0x7fffu + ((u >> 16) & 1u)) >> 16;   // round-to-nearest-even
  return (unsigned short)r;
}

// L2-scope (same-XCD) ops: bypass L1 (sc0), hit the shared per-XCD L2.
__device__ __forceinline__ unsigned int ld_sc0(const int* p) {
  unsigned int v;
  asm volatile("global_load_dword %0, %1, off sc0\n\ts_waitcnt vmcnt(0)"
               : "=v"(v) : "v"(p) : "memory");
  return v;
}
__device__ __forceinline__ void st_sc0(unsigned int* p, unsigned int v) {
  asm volatile("global_store_dword %0, %1, off sc0" :: "v"(p), "v"(v) : "memory");
}

// ---- prep: weights -> wx (x-part, [dir][n][k<512]) + wh (h-part frag image); zero flags
__global__ void prep_kernel(const float* __restrict__ Wih_f, const float* __restrict__ Whh_f,
                            const float* __restrict__ Wih_b, const float* __restrict__ Whh_b,
                            unsigned short* __restrict__ wx,
                            unsigned short* __restrict__ wh,
                            int* __restrict__ flags)
{
  size_t tid0 = (size_t)blockIdx.x * blockDim.x + threadIdx.x;
  size_t stride = (size_t)gridDim.x * blockDim.x;

  const size_t WC = (size_t)2 * GG * KK;   // 2^22
  for (size_t idx = tid0; idx < WC; idx += stride) {
    int dir = (int)(idx >> 21);
    int rem = (int)(idx & ((1u << 21) - 1));
    int n = rem >> 10;        // 0..2047
    int k = rem & 1023;       // 0..1023
    if (k < II) {
      const float* Wih = dir ? Wih_b : Wih_f;
      wx[(size_t)dir * GG * II + (size_t)n * II + k] = f2bf(Wih[(size_t)n * II + k]);
    } else {
      const float* Whh = dir ? Whh_b : Whh_f;
      int kk = k - II;            // 0..511
      int kc = kk >> 5;           // 0..15
      int r  = kk & 31;
      int quad = r >> 3;          // 0..3
      int e  = r & 7;             // 0..7
      int g   = n >> 9;           // 0..3
      int blk = (n >> 4) & 31;    // col-16-slice 0..31
      int j   = n & 15;           // 0..15
      size_t lidx = ((size_t)((g * 16 + kc) * 4 + quad) * 16 + j) * 8 + e;
      wh[((size_t)dir * 32 + blk) * 32768 + lidx] = f2bf(Whh[(size_t)n * HH + kk]);
    }
  }

  for (size_t idx = tid0; idx < FLAG_INTS; idx += stride) flags[idx] = 0;
}

// ---- x -> bf16
__global__ void xconv_kernel(const float* __restrict__ x, unsigned short* __restrict__ xb) {
  size_t i = (size_t)blockIdx.x * blockDim.x + threadIdx.x;
  size_t stride = (size_t)gridDim.x * blockDim.x;
  const size_t n4 = (size_t)TT * BB * II / 4;
  const float4* xp = (const float4*)x;
  ushort4* op = (ushort4*)xb;
  for (; i < n4; i += stride) {
    float4 v = xp[i];
    ushort4 o;
    o.x = f2bf(v.x); o.y = f2bf(v.y); o.z = f2bf(v.z); o.w = f2bf(v.w);
    op[i] = o;
  }
}

// ---- persistent bidirectional LSTM, round 7: XCD self-staffing
//
// 256 blocks launched. Each block reads its REAL XCC_ID and claims rank via a
// per-XCD counter. The first two XCDs to reach 32 members become dir0/dir1;
// the 32nd claimer of each publishes the selection, and the second one CASes
// the global decision word to FAST. All intra-dir h/flag transport then runs
// at sc0 (shared per-XCD L2, ~200cy) instead of agent scope (MALL, ~1us).
// If staffing can't complete (weird placement / broken XCC read), a timeout
// CASes ABORT and a consistent fallback cohort re-forms with the proven
// agent-scope protocol (identical math => even a double-run is benign).
// The poll uses atomic LOADS only (agent loads always observe MALL) — the old
// fetch_add escalation created an RMW storm that queued ahead of the very
// flag store being awaited.
// ctrl words live in the (never-polled) dir0/t=511 flag lines; producers skip
// the flag store at t==TT-1.
__global__ __launch_bounds__(256, 1) void lstm_persist(
    const unsigned short* __restrict__ xb,
    const unsigned short* __restrict__ wx,
    const unsigned short* __restrict__ wh,
    int* __restrict__ flags,
    const float* __restrict__ h0,
    const float* __restrict__ c0,
    const float* __restrict__ b_f,
    const float* __restrict__ b_b,
    float* __restrict__ out,
    unsigned short* __restrict__ hx)
{
  __shared__ int shm[4];
  const int tid  = threadIdx.x;
  const int lane = tid & 63;
  const int l15  = lane & 15;
  const int quad = lane >> 4;
  const int wid  = tid >> 6;
  const int m0   = wid << 4;

  int* ctrl = flags + (size_t)511 * 1024;   // dir0, t=511 line region (never polled)
  // ctrl[0..7]: per-XCD claim counters   ctrl[8]: full-group slot counter
  // ctrl[10]: decision (1=FAST, 2=ABORT) ctrl[16]: fallback cohort counter
  // ctrl[20],ctrl[21]: xcc+1 of dir0/dir1 groups

  if (tid == 0) {
    unsigned xcc = 0;
    asm volatile("s_getreg_b32 %0, hwreg(HW_REG_XCC_ID)" : "=s"(xcc));
    if (xcc > 7u) xcc = 7u;
    int rank = __hip_atomic_fetch_add(&ctrl[xcc], 1, __ATOMIC_RELAXED, __HIP_MEMORY_SCOPE_AGENT);
    if (rank == 31) {                       // 32nd member: group is full -> claim a dir slot
      int slot = __hip_atomic_fetch_add(&ctrl[8], 1, __ATOMIC_RELAXED, __HIP_MEMORY_SCOPE_AGENT);
      if (slot < 2) {
        __hip_atomic_store(&ctrl[20 + slot], (int)xcc + 1,
                           __ATOMIC_RELEASE, __HIP_MEMORY_SCOPE_AGENT);
        if (slot == 1) {
          int exp = 0;
          __hip_atomic_compare_exchange_strong(&ctrl[10], &exp, 1,
              __ATOMIC_RELEASE, __ATOMIC_RELAXED, __HIP_MEMORY_SCOPE_AGENT);
        }
      }
    }
    // wait for the committed decision (timeout -> ABORT)
    unsigned long long tb = __builtin_amdgcn_s_memrealtime();
    int dec;
    while ((dec = __hip_atomic_load(&ctrl[10], __ATOMIC_ACQUIRE, __HIP_MEMORY_SCOPE_AGENT)) == 0) {
      if (__builtin_amdgcn_s_memrealtime() - tb > 100000ull) {
        int exp = 0;
        __hip_atomic_compare_exchange_strong(&ctrl[10], &exp, 2,
            __ATOMIC_RELEASE, __ATOMIC_RELAXED, __HIP_MEMORY_SCOPE_AGENT);
      }
      __builtin_amdgcn_s_sleep(8);
    }
    int dir = -1, blk = 0;
    if (dec == 1) {
      int xa, xbv;
      while ((xa = __hip_atomic_load(&ctrl[20], __ATOMIC_ACQUIRE, __HIP_MEMORY_SCOPE_AGENT)) == 0)
        __builtin_amdgcn_s_sleep(2);
      while ((xbv = __hip_atomic_load(&ctrl[21], __ATOMIC_ACQUIRE, __HIP_MEMORY_SCOPE_AGENT)) == 0)
        __builtin_amdgcn_s_sleep(2);
      if (rank < 32) {
        if ((int)xcc == xa - 1)       { dir = 0; blk = rank; }
        else if ((int)xcc == xbv - 1) { dir = 1; blk = rank; }
      }
    } else {
      int r2 = __hip_atomic_fetch_add(&ctrl[16], 1, __ATOMIC_RELAXED, __HIP_MEMORY_SCOPE_AGENT);
      if (r2 < 64) { dir = r2 >> 5; blk = r2 & 31; }
    }
    shm[0] = dir; shm[1] = blk; shm[2] = dec;
  }
  __syncthreads();
  const int dir  = shm[0];
  const int blk  = shm[1];
  const bool fast = (shm[2] == 1);
  if (dir < 0) return;                      // unselected block
  const int j0 = blk << 4;

  // ---- h-part weights resident in VGPRs: frag (g,kc) at wb[g*16+kc] ----
  short8 wb[64];
  {
    const unsigned short* wsrc = wh + ((size_t)dir * 32 + blk) * 32768
                                    + (size_t)(quad * 16 + l15) * 8;
#pragma unroll
    for (int f = 0; f < 64; ++f)
      wb[f] = *(const short8*)(wsrc + (size_t)f * 512);
  }

  const float* bias = dir ? b_b : b_f;
  float bs[4];
#pragma unroll
  for (int g = 0; g < 4; ++g) bs[g] = bias[g * HH + j0 + l15];

  float cst[4];
#pragma unroll
  for (int r = 0; r < 4; ++r)
    cst[r] = c0[(size_t)dir * BB * HH + (size_t)(m0 + quad * 4 + r) * HH + j0 + l15];

  const unsigned short* wxrow[4];
#pragma unroll
  for (int g = 0; g < 4; ++g)
    wxrow[g] = wx + (size_t)dir * GG * II + (size_t)(g * HH + j0 + l15) * II + quad * 8;

  int* fl_dir = flags + (size_t)dir * TT * 1024;

  for (int t = 0; t < TT; ++t) {
    const int tt2 = dir ? (TT - 1 - t) : t;

    floatx4 acc[4];
#pragma unroll
    for (int g = 0; g < 4; ++g) acc[g] = (floatx4){0.f, 0.f, 0.f, 0.f};

    // ---- x contribution (k = 0..511): independent of h, overlaps the wait ----
    {
      const unsigned short* arow = xb + (size_t)tt2 * BB * II + (size_t)(m0 + l15) * II + quad * 8;
#pragma unroll
      for (int kc = 0; kc < 16; ++kc) {
        short8 a = *(const short8*)(arow + kc * 32);
#pragma unroll
        for (int g = 0; g < 4; ++g) {
          short8 b = *(const short8*)(wxrow[g] + kc * 32);
          acc[g] = __builtin_amdgcn_mfma_f32_16x16x32_bf16(a, b, acc[g], 0, 0, 0);
        }
      }
    }

    // ---- wait for h_{t-1}: per-wave poll, LOADS only ----
    if (t > 0) {
      int* fl = fl_dir + (((size_t)(t - 1) << 5) + (lane & 31)) * 32 + wid * 8;
      int vv = 1;
      while (true) {
        if (lane < 32)
          vv = fast ? (int)ld_sc0(fl)
                    : __hip_atomic_load(fl, __ATOMIC_RELAXED, __HIP_MEMORY_SCOPE_AGENT);
        if (__ballot(vv > 0) == ~0ull) break;
        __builtin_amdgcn_s_sleep(1);
      }
      asm volatile("" ::: "memory");   // keep h loads below the wait
    }

    // ---- h contribution (k = 512..1023), B from VGPRs ----
    if (t > 0) {
      const unsigned short* hrow = hx + (((size_t)dir * TT + (t - 1)) * BB + (size_t)(m0 + l15)) * HH + quad * 8;
#pragma unroll
      for (int kc = 0; kc < 16; ++kc) {
        short8 a = *(const short8*)(hrow + kc * 32);
#pragma unroll
        for (int g = 0; g < 4; ++g)
          acc[g] = __builtin_amdgcn_mfma_f32_16x16x32_bf16(a, wb[g * 16 + kc], acc[g], 0, 0, 0);
      }
    } else {
      const float* hrow = h0 + (size_t)dir * BB * HH + (size_t)(m0 + l15) * HH + quad * 8;
#pragma unroll
      for (int kc = 0; kc < 16; ++kc) {
        float4 v0f = *(const float4*)(hrow + (size_t)kc * 32);
        float4 v1f = *(const float4*)(hrow + (size_t)kc * 32 + 4);
        short8 a;
        a[0] = (short)f2bf(v0f.x); a[1] = (short)f2bf(v0f.y);
        a[2] = (short)f2bf(v0f.z); a[3] = (short)f2bf(v0f.w);
        a[4] = (short)f2bf(v1f.x); a[5] = (short)f2bf(v1f.y);
        a[6] = (short)f2bf(v1f.z); a[7] = (short)f2bf(v1f.w);
#pragma unroll
        for (int g = 0; g < 4; ++g)
          acc[g] = __builtin_amdgcn_mfma_f32_16x16x32_bf16(a, wb[g * 16 + kc], acc[g], 0, 0, 0);
      }
    }

    // ---- gates + state update ----
    float hf[4];
#pragma unroll
    for (int r = 0; r < 4; ++r) {
      float gi = acc[0][r] + bs[0];
      float gf = acc[1][r] + bs[1];
      float gg = acc[2][r] + bs[2];
      float go = acc[3][r] + bs[3];
      float si = 1.f / (1.f + __expf(-gi));
      float sf = 1.f / (1.f + __expf(-gf));
      float tg = 2.f / (1.f + __expf(-2.f * gg)) - 1.f;
      float so = 1.f / (1.f + __expf(-go));
      float c  = sf * cst[r] + si * tg;
      cst[r] = c;
      float th = 2.f / (1.f + __expf(-2.f * c)) - 1.f;
      hf[r] = so * th;
    }

    // ---- publish bf16 h: pack column pairs into dwords ----
    unsigned int pk[4];
#pragma unroll
    for (int r = 0; r < 4; ++r) {
      unsigned int mine  = f2bf(hf[r]);
      unsigned int other = (unsigned int)(unsigned short)__shfl_xor((int)mine, 1);
      pk[r] = (l15 & 1) ? (other | (mine << 16)) : (mine | (other << 16));
    }
    unsigned short* hxt = hx + ((size_t)dir * TT + t) * BB * HH + (j0 + (l15 & ~1));
    const int rb = (l15 & 1) << 1;
#pragma unroll
    for (int rr = 0; rr < 2; ++rr) {
      int row = m0 + quad * 4 + rb + rr;
      unsigned int* addr = (unsigned int*)(hxt + (size_t)row * HH);
      if (fast) st_sc0(addr, pk[rb + rr]);
      else __hip_atomic_store(addr, pk[rb + rr],
                              __ATOMIC_RELAXED, __HIP_MEMORY_SCOPE_AGENT);
    }
    asm volatile("s_waitcnt vmcnt(0)" ::: "memory");   // h stores visible at transport scope
    if (lane == 0 && t != TT - 1) {                    // t=TT-1 lines host ctrl; never polled
      int* flp = fl_dir + (((size_t)t << 5) + blk) * 32 + wid * 8;
      if (fast) st_sc0((unsigned int*)flp, 1u);
      else __hip_atomic_store(flp, 1, __ATOMIC_RELAXED, __HIP_MEMORY_SCOPE_AGENT);
    }

    // fp32 output (cached, off critical path, flushed at kernel end)
    float* orow = out + (size_t)tt2 * BB * 2 * HH + (size_t)dir * HH + j0 + l15;
#pragma unroll
    for (int r = 0; r < 4; ++r)
      orow[(size_t)(m0 + quad * 4 + r) * 2 * HH] = hf[r];
  }
}

// ---- minimal legacy fallback (tiny workspace): fp32 x, exchange fp32 h via out
__global__ __launch_bounds__(256, 1) void lstm_legacy(
    const float* __restrict__ x_f32,
    const unsigned short* __restrict__ wx,
    const unsigned short* __restrict__ wh,
    int* __restrict__ flags,
    const float* __restrict__ h0,
    const float* __restrict__ c0,
    const float* __restrict__ b_f,
    const float* __restrict__ b_b,
    float* __restrict__ out)
{
  const int bid  = blockIdx.x;
  const int dir  = bid >> 5;
  const int blk  = bid & 31;
  const int j0   = blk << 4;
  const int tid  = threadIdx.x;
  const int lane = tid & 63;
  const int l15  = lane & 15;
  const int quad = lane >> 4;
  const int wid  = tid >> 6;
  const int m0   = wid << 4;

  short8 wb[64];
  {
    const unsigned short* wsrc = wh + ((size_t)dir * 32 + blk) * 32768
                                    + (size_t)(quad * 16 + l15) * 8;
#pragma unroll
    for (int f = 0; f < 64; ++f)
      wb[f] = *(const short8*)(wsrc + (size_t)f * 512);
  }
  const float* bias = dir ? b_b : b_f;
  float bs[4];
#pragma unroll
  for (int g = 0; g < 4; ++g) bs[g] = bias[g * HH + j0 + l15];
  float cst[4];
#pragma unroll
  for (int r = 0; r < 4; ++r)
    cst[r] = c0[(size_t)dir * BB * HH + (size_t)(m0 + quad * 4 + r) * HH + j0 + l15];
  const unsigned short* wxrow[4];
#pragma unroll
  for (int g = 0; g < 4; ++g)
    wxrow[g] = wx + (size_t)dir * GG * II + (size_t)(g * HH + j0 + l15) * II + quad * 8;
  int* fl_dir = flags + (size_t)dir * TT * 1024;

  for (int t = 0; t < TT; ++t) {
    const int tt2 = dir ? (TT - 1 - t) : t;
    floatx4 acc[4];
#pragma unroll
    for (int g = 0; g < 4; ++g) acc[g] = (floatx4){0.f, 0.f, 0.f, 0.f};
    const float* arow = x_f32 + (size_t)tt2 * BB * II + (size_t)(m0 + l15) * II + quad * 8;
#pragma unroll
    for (int kc = 0; kc < 16; ++kc) {
      float4 v0 = *(const float4*)(arow + kc * 32);
      float4 v1 = *(const float4*)(arow + kc * 32 + 4);
      short8 a;
      a[0] = (short)f2bf(v0.x); a[1] = (short)f2bf(v0.y);
      a[2] = (short)f2bf(v0.z); a[3] = (short)f2bf(v0.w);
      a[4] = (short)f2bf(v1.x); a[5] = (short)f2bf(v1.y);
      a[6] = (short)f2bf(v1.z); a[7] = (short)f2bf(v1.w);
#pragma unroll
      for (int g = 0; g < 4; ++g) {
        short8 b = *(const short8*)(wxrow[g] + kc * 32);
        acc[g] = __builtin_amdgcn_mfma_f32_16x16x32_bf16(a, b, acc[g], 0, 0, 0);
      }
    }
    if (t > 0) {
      int* fl = fl_dir + (((size_t)(t - 1) << 5) + (lane & 31)) * 32 + wid * 8;
      int vv = 1;
      while (true) {
        if (lane < 32)
          vv = __hip_atomic_load(fl, __ATOMIC_RELAXED, __HIP_MEMORY_SCOPE_AGENT);
        if (__ballot(vv > 0) == ~0ull) break;
        __builtin_amdgcn_s_sleep(1);
      }
      asm volatile("" ::: "memory");
    }
    const float* hrow;
    if (t == 0) hrow = h0 + (size_t)dir * BB * HH + (size_t)(m0 + l15) * HH + quad * 8;
    else {
      const int tp = dir ? (TT - t) : (t - 1);
      hrow = out + (size_t)tp * BB * 2 * HH + (size_t)(m0 + l15) * 2 * HH + (size_t)dir * HH + quad * 8;
    }
#pragma unroll
    for (int kc = 0; kc < 16; ++kc) {
      float4 v0 = *(const float4*)(hrow + (size_t)kc * 32);
      float4 v1 = *(const float4*)(hrow + (size_t)kc * 32 + 4);
      short8 a;
      a[0] = (short)f2bf(v0.x); a[1] = (short)f2bf(v0.y);
      a[2] = (short)f2bf(v0.z); a[3] = (short)f2bf(v0.w);
      a[4] = (short)f2bf(v1.x); a[5] = (short)f2bf(v1.y);
      a[6] = (short)f2bf(v1.z); a[7] = (short)f2bf(v1.w);
#pragma unroll
      for (int g = 0; g < 4; ++g)
        acc[g] = __builtin_amdgcn_mfma_f32_16x16x32_bf16(a, wb[g * 16 + kc], acc[g], 0, 0, 0);
    }
    float hf[4];
#pragma unroll
    for (int r = 0; r < 4; ++r) {
      float gi = acc[0][r] + bs[0];
      float gf = acc[1][r] + bs[1];
      float gg = acc[2][r] + bs[2];
      float go = acc[3][r] + bs[3];
      float si = 1.f / (1.f + __expf(-gi));
      float sf = 1.f / (1.f + __expf(-gf));
      float tg = 2.f / (1.f + __expf(-2.f * gg)) - 1.f;
      float so = 1.f / (1.f + __expf(-go));
      float c  = sf * cst[r] + si * tg;
      cst[r] = c;
      float th = 2.f / (1.f + __expf(-2.f * c)) - 1.f;
      hf[r] = so * th;
    }
    float* orow = out + (size_t)tt2 * BB * 2 * HH + (size_t)dir * HH + j0 + l15;
#pragma unroll
    for (int r = 0; r < 4; ++r)
      __hip_atomic_store(&orow[(size_t)(m0 + quad * 4 + r) * 2 * HH], hf[r],
                         __ATOMIC_RELAXED, __HIP_MEMORY_SCOPE_AGENT);
    asm volatile("s_waitcnt vmcnt(0)" ::: "memory");
    if (lane == 0)
      __hip_atomic_store(fl_dir + (((size_t)t << 5) + blk) * 32 + wid * 8, 1,
                         __ATOMIC_RELAXED, __HIP_MEMORY_SCOPE_AGENT);
  }
}

extern "C" void kernel_launch(void* const* d_in, const int* in_sizes, int n_in,
                              void* d_out, int out_size, void* d_ws, size_t ws_size,
                              hipStream_t stream)
{
  (void)in_sizes; (void)n_in; (void)out_size;
  const float* x     = (const float*)d_in[0];
  const float* h0    = (const float*)d_in[1];
  const float* c0    = (const float*)d_in[2];
  const float* Wih_f = (const float*)d_in[3];
  const float* Whh_f = (const float*)d_in[4];
  const float* b_f   = (const float*)d_in[5];
  const float* Wih_b = (const float*)d_in[6];
  const float* Whh_b = (const float*)d_in[7];
  const float* b_b   = (const float*)d_in[8];
  float* out = (float*)d_out;
  char* ws = (char*)d_ws;

  const size_t NEED = WX_BYTES + WH_BYTES + XB_BYTES + FLAG_BYTES + HX_BYTES;
  const bool big = ws_size >= NEED;

  unsigned short* wx = (unsigned short*)ws;
  unsigned short* wh = (unsigned short*)(ws + WX_BYTES);
  unsigned short* xb = (unsigned short*)(ws + WX_BYTES + WH_BYTES);
  int* flags;
  unsigned short* hxp = nullptr;
  if (big) {
    flags = (int*)(ws + WX_BYTES + WH_BYTES + XB_BYTES);
    hxp   = (unsigned short*)(ws + WX_BYTES + WH_BYTES + XB_BYTES + FLAG_BYTES);
  } else {
    flags = (int*)(ws + WX_BYTES + WH_BYTES);
  }

  prep_kernel<<<512, 256, 0, stream>>>(Wih_f, Whh_f, Wih_b, Whh_b, wx, wh, flags);
  if (big) {
    xconv_kernel<<<2048, 256, 0, stream>>>(x, xb);
    lstm_persist<<<256, 256, 0, stream>>>(xb, wx, wh, flags, h0, c0, b_f, b_b, out, hxp);
  } else {
    lstm_legacy<<<64, 256, 0, stream>>>(x, wx, wh, flags, h0, c0, b_f, b_b, out);
  }
}

// Round 5
// 3610.661 us; speedup vs baseline: 1.7333x; 1.5838x over previous
//
#include <hip/hip_runtime.h>
#include <stdint.h>

#define TT 512
#define BB 64
#define II 512
#define HH 512
#define GG 2048   // 4H
#define KK 1024   // I + H

typedef short short8 __attribute__((ext_vector_type(8)));
typedef float floatx4 __attribute__((ext_vector_type(4)));

// workspace layout (108 MB total, same budget as rounds 1-3)
static constexpr size_t WF_BYTES   = (size_t)2 * 32 * 65536 * 2;    // 8 MB bf16 frag image [dir][blk][p][g][kc][quadL][j][e]
static constexpr size_t XA_BYTES   = (size_t)TT * BB * II * 2;      // 32 MB bf16 A-frag image [t][mt][kc][quadL][l15][e]
static constexpr size_t FLAG_INTS  = (size_t)2 * TT * 32 * 32;      // 4 MB: flags[dir][t][blk] 128B lines; wid*8 sub-slot
static constexpr size_t FLAG_BYTES = FLAG_INTS * 4;
static constexpr size_t HX_BYTES   = (size_t)2 * TT * BB * HH * 2;  // 64 MB bf16 h-exchange, A-frag layout [dir][t][mt][kc][quadL][l15][e]

__device__ __forceinline__ unsigned short f2bf(float f) {
  unsigned int u = __float_as_uint(f);
  unsigned int r = (u + 0x7fffu + ((u >> 16) & 1u)) >> 16;   // round-to-nearest-even
  return (unsigned short)r;
}

// ---- prep: all weights -> wf frag image; zero flags
// wf[(dir*32+blk)*65536 + (((p*4+g)*16+kc)*4+quadL)*128 + j*8 + e]
//   = W_p[n = g*512 + blk*16 + j][kk = kc*32 + quadL*8 + e]   (p=0: W_ih, p=1: W_hh)
__global__ void prep_kernel(const float* __restrict__ Wih_f, const float* __restrict__ Whh_f,
                            const float* __restrict__ Wih_b, const float* __restrict__ Whh_b,
                            unsigned short* __restrict__ wf,
                            int* __restrict__ flags)
{
  size_t tid0 = (size_t)blockIdx.x * blockDim.x + threadIdx.x;
  size_t stride = (size_t)gridDim.x * blockDim.x;

  const size_t WC = (size_t)2 * GG * KK;   // 2^22
  for (size_t idx = tid0; idx < WC; idx += stride) {
    int dir = (int)(idx >> 21);
    int rem = (int)(idx & ((1u << 21) - 1));
    int n = rem >> 10;        // 0..2047
    int k = rem & 1023;       // 0..1023
    int p  = (k >= II) ? 1 : 0;
    int kk = k & 511;
    const float* W = p ? (dir ? Whh_b : Whh_f) : (dir ? Wih_b : Wih_f);
    float v = W[(size_t)n * 512 + kk];
    int kc = kk >> 5;
    int quadL = (kk >> 3) & 3;
    int e  = kk & 7;
    int g   = n >> 9;
    int blk = (n >> 4) & 31;
    int j   = n & 15;
    size_t lidx = ((size_t)((p * 4 + g) * 16 + kc) * 4 + quadL) * 128 + (size_t)j * 8 + e;
    wf[(size_t)(dir * 32 + blk) * 65536 + lidx] = f2bf(v);
  }

  for (size_t idx = tid0; idx < FLAG_INTS; idx += stride) flags[idx] = 0;
}

// ---- x -> bf16 A-fragment image: xa[((t*4+mt)*16+kc)*512 + quadL*128 + l15*8 + e]
//      = bf16(x[t][b = mt*16 + l15][i = kc*32 + quadL*8 + e])
__global__ void xconv_kernel(const float* __restrict__ x, unsigned short* __restrict__ xa) {
  size_t i4 = (size_t)blockIdx.x * blockDim.x + threadIdx.x;
  size_t stride = (size_t)gridDim.x * blockDim.x;
  const size_t n4 = (size_t)TT * BB * II / 4;
  const float4* xp = (const float4*)x;
  for (; i4 < n4; i4 += stride) {
    int t   = (int)(i4 >> 13);          // BB*II/4 = 8192 float4 per t
    int rem = (int)(i4 & 8191);
    int b   = rem >> 7;                 // II/4 = 128 float4 per row
    int i0  = (rem & 127) << 2;         // element index, multiple of 4
    float4 v = xp[i4];
    ushort4 o;
    o.x = f2bf(v.x); o.y = f2bf(v.y); o.z = f2bf(v.z); o.w = f2bf(v.w);
    size_t base = ((((size_t)t * 4 + (b >> 4)) * 16 + (i0 >> 5)) * 4 + ((i0 >> 3) & 3)) * 128
                + (size_t)(b & 15) * 8 + (i0 & 7);
    *(ushort4*)(xa + base) = o;         // 8B aligned: (i0&7) in {0,4}
  }
}

// ---- persistent bidirectional LSTM, round 9
//
// Theory: rounds 1-3 proved transport scope / poll mechanics are NOT the
// bottleneck (sc0 same-XCD transport: zero delta). The invariant ~11us/step is
// intra-block memory-pipe serialization: every in-loop load was a 64-lane load
// touching 16 cache lines (1KB-strided rows), ~96 such loads/wave/step.
// Round-9 changes:
//  * BOTH B operands (x-part + h-part weights) live in LDS: 128 KB frag image
//    staged once. Zero in-loop weight VMEM.
//  * x staged as A-fragment image (xa): each wave A-load = contiguous 1KB.
//  * h exchanged in A-fragment layout (hx): producer dword stores land exactly
//    where the consumer does contiguous 1KB fragment loads.
//  * protocol identical to round 1 (proven): relaxed agent data stores ->
//    vmcnt(0) -> relaxed agent flag store; load-only poll; per-wave flags;
//    no in-loop barriers. Staffing/sc0 machinery dropped (measured: no gain).
__global__ __launch_bounds__(256, 1) void lstm_persist(
    const unsigned short* __restrict__ xa,
    const unsigned short* __restrict__ wf,
    int* __restrict__ flags,
    const float* __restrict__ h0,
    const float* __restrict__ c0,
    const float* __restrict__ b_f,
    const float* __restrict__ b_b,
    float* __restrict__ out,
    unsigned short* __restrict__ hx)
{
  __shared__ unsigned short w_lds[65536];   // 128 KB: [p][g][kc][quadL][j][e]

  const int bid  = blockIdx.x;
  const int dir  = bid >> 5;
  const int blk  = bid & 31;
  const int j0   = blk << 4;
  const int tid  = threadIdx.x;
  const int lane = tid & 63;
  const int l15  = lane & 15;
  const int quad = lane >> 4;
  const int wid  = tid >> 6;
  const int m0   = wid << 4;

  // ---- stage 128 KB of B-fragments into LDS (once) ----
  {
    const uint4* src = (const uint4*)(wf + (size_t)(dir * 32 + blk) * 65536);
    uint4* dst = (uint4*)w_lds;
#pragma unroll
    for (int i = 0; i < 32; ++i) dst[tid + 256 * i] = src[tid + 256 * i];
  }

  const float* bias = dir ? b_b : b_f;
  float bs[4];
#pragma unroll
  for (int g = 0; g < 4; ++g) bs[g] = bias[g * HH + j0 + l15];

  // c state in registers: C/D layout -> row = m0 + quad*4 + r, col = j0 + l15
  float cst[4];
#pragma unroll
  for (int r = 0; r < 4; ++r)
    cst[r] = c0[(size_t)dir * BB * HH + (size_t)(m0 + quad * 4 + r) * HH + j0 + l15];

  const int wl = quad * 128 + l15 * 8;   // per-lane offset inside a 512-short fragment
  int* fl_dir = flags + (size_t)dir * TT * 1024;

  __syncthreads();   // LDS weights ready

  for (int t = 0; t < TT; ++t) {
    const int tt2 = dir ? (TT - 1 - t) : t;

    floatx4 acc[4];
#pragma unroll
    for (int g = 0; g < 4; ++g) acc[g] = (floatx4){0.f, 0.f, 0.f, 0.f};

    // ---- x contribution (k = 0..511): A from xa (contiguous 1KB/frag), B from LDS ----
    {
      const unsigned short* arow = xa + ((size_t)tt2 * 4 + wid) * 8192 + wl;
#pragma unroll
      for (int kc = 0; kc < 16; ++kc) {
        short8 a = *(const short8*)(arow + kc * 512);
#pragma unroll
        for (int g = 0; g < 4; ++g) {
          short8 b = *(const short8*)(&w_lds[(g * 16 + kc) * 512 + wl]);
          acc[g] = __builtin_amdgcn_mfma_f32_16x16x32_bf16(a, b, acc[g], 0, 0, 0);
        }
      }
    }

    // ---- wait for h_{t-1}: per-wave poll, relaxed agent LOADS only ----
    if (t > 0) {
      int* fl = fl_dir + (((size_t)(t - 1) << 5) + (lane & 31)) * 32 + wid * 8;
      int vv = 1;
      while (true) {
        if (lane < 32)
          vv = __hip_atomic_load(fl, __ATOMIC_RELAXED, __HIP_MEMORY_SCOPE_AGENT);
        if (__ballot(vv > 0) == ~0ull) break;
        __builtin_amdgcn_s_sleep(1);
      }
      asm volatile("" ::: "memory");   // keep h loads below the wait
    }

    // ---- h contribution (k = 512..1023): A from hx (contiguous), B from LDS ----
    if (t > 0) {
      const unsigned short* hrow = hx + ((size_t)(dir * TT + (t - 1)) * 4 + wid) * 8192 + wl;
#pragma unroll
      for (int kc = 0; kc < 16; ++kc) {
        short8 a = *(const short8*)(hrow + kc * 512);
#pragma unroll
        for (int g = 0; g < 4; ++g) {
          short8 b = *(const short8*)(&w_lds[(64 + g * 16 + kc) * 512 + wl]);
          acc[g] = __builtin_amdgcn_mfma_f32_16x16x32_bf16(a, b, acc[g], 0, 0, 0);
        }
      }
    } else {
      const float* hrow = h0 + (size_t)dir * BB * HH + (size_t)(m0 + l15) * HH + quad * 8;
#pragma unroll
      for (int kc = 0; kc < 16; ++kc) {
        float4 v0f = *(const float4*)(hrow + (size_t)kc * 32);
        float4 v1f = *(const float4*)(hrow + (size_t)kc * 32 + 4);
        short8 a;
        a[0] = (short)f2bf(v0f.x); a[1] = (short)f2bf(v0f.y);
        a[2] = (short)f2bf(v0f.z); a[3] = (short)f2bf(v0f.w);
        a[4] = (short)f2bf(v1f.x); a[5] = (short)f2bf(v1f.y);
        a[6] = (short)f2bf(v1f.z); a[7] = (short)f2bf(v1f.w);
#pragma unroll
        for (int g = 0; g < 4; ++g) {
          short8 b = *(const short8*)(&w_lds[(64 + g * 16 + kc) * 512 + wl]);
          acc[g] = __builtin_amdgcn_mfma_f32_16x16x32_bf16(a, b, acc[g], 0, 0, 0);
        }
      }
    }

    // ---- gates + state update ----
    float hf[4];
#pragma unroll
    for (int r = 0; r < 4; ++r) {
      float gi = acc[0][r] + bs[0];
      float gf = acc[1][r] + bs[1];
      float gg = acc[2][r] + bs[2];
      float go = acc[3][r] + bs[3];
      float si = 1.f / (1.f + __expf(-gi));
      float sf = 1.f / (1.f + __expf(-gf));
      float tg = 2.f / (1.f + __expf(-2.f * gg)) - 1.f;
      float so = 1.f / (1.f + __expf(-go));
      float c  = sf * cst[r] + si * tg;
      cst[r] = c;
      float th = 2.f / (1.f + __expf(-2.f * c)) - 1.f;
      hf[r] = so * th;
    }

    // ---- publish bf16 h directly in the consumer's A-fragment layout ----
    // value (row = m0 + quad*4 + r, col = j0 + l15) -> hx[t][mt=wid][kc=col>>5]
    //   [quadL=(col>>3)&3][l15=row&15][e=col&7]; col pairs packed into dwords.
    unsigned int pk[4];
#pragma unroll
    for (int r = 0; r < 4; ++r) {
      unsigned int mine  = f2bf(hf[r]);
      unsigned int other = (unsigned int)(unsigned short)__shfl_xor((int)mine, 1);
      pk[r] = (l15 & 1) ? (other | (mine << 16)) : (mine | (other << 16));
    }
    {
      const int kcP = blk >> 1;
      const int qP  = ((blk & 1) << 1) + (l15 >> 3);
      unsigned short* hb = hx + ((size_t)(dir * TT + t) * 4 + wid) * 8192
                              + kcP * 512 + qP * 128 + (l15 & 6);
      const int rb = (l15 & 1) << 1;
#pragma unroll
      for (int rr = 0; rr < 2; ++rr) {
        int rowl = quad * 4 + rb + rr;
        __hip_atomic_store((unsigned int*)(hb + rowl * 8), pk[rb + rr],
                           __ATOMIC_RELAXED, __HIP_MEMORY_SCOPE_AGENT);
      }
    }
    asm volatile("s_waitcnt vmcnt(0)" ::: "memory");   // h stores globally visible
    if (lane == 0)
      __hip_atomic_store(fl_dir + (((size_t)t << 5) + blk) * 32 + wid * 8, 1,
                         __ATOMIC_RELAXED, __HIP_MEMORY_SCOPE_AGENT);

    // fp32 output (cached, off critical path, flushed at kernel end)
    float* orow = out + (size_t)tt2 * BB * 2 * HH + (size_t)dir * HH + j0 + l15;
#pragma unroll
    for (int r = 0; r < 4; ++r)
      orow[(size_t)(m0 + quad * 4 + r) * 2 * HH] = hf[r];
  }
}

// ---- minimal legacy fallback (tiny workspace): fp32 x, fp32 h via out, B from global wf
__global__ __launch_bounds__(256, 1) void lstm_legacy(
    const float* __restrict__ x_f32,
    const unsigned short* __restrict__ wf,
    int* __restrict__ flags,
    const float* __restrict__ h0,
    const float* __restrict__ c0,
    const float* __restrict__ b_f,
    const float* __restrict__ b_b,
    float* __restrict__ out)
{
  const int bid  = blockIdx.x;
  const int dir  = bid >> 5;
  const int blk  = bid & 31;
  const int j0   = blk << 4;
  const int tid  = threadIdx.x;
  const int lane = tid & 63;
  const int l15  = lane & 15;
  const int quad = lane >> 4;
  const int wid  = tid >> 6;
  const int m0   = wid << 4;

  const unsigned short* wblk = wf + (size_t)(dir * 32 + blk) * 65536;
  const int wl = quad * 128 + l15 * 8;

  const float* bias = dir ? b_b : b_f;
  float bs[4];
#pragma unroll
  for (int g = 0; g < 4; ++g) bs[g] = bias[g * HH + j0 + l15];
  float cst[4];
#pragma unroll
  for (int r = 0; r < 4; ++r)
    cst[r] = c0[(size_t)dir * BB * HH + (size_t)(m0 + quad * 4 + r) * HH + j0 + l15];
  int* fl_dir = flags + (size_t)dir * TT * 1024;

  for (int t = 0; t < TT; ++t) {
    const int tt2 = dir ? (TT - 1 - t) : t;
    floatx4 acc[4];
#pragma unroll
    for (int g = 0; g < 4; ++g) acc[g] = (floatx4){0.f, 0.f, 0.f, 0.f};
    const float* arow = x_f32 + (size_t)tt2 * BB * II + (size_t)(m0 + l15) * II + quad * 8;
#pragma unroll
    for (int kc = 0; kc < 16; ++kc) {
      float4 v0 = *(const float4*)(arow + kc * 32);
      float4 v1 = *(const float4*)(arow + kc * 32 + 4);
      short8 a;
      a[0] = (short)f2bf(v0.x); a[1] = (short)f2bf(v0.y);
      a[2] = (short)f2bf(v0.z); a[3] = (short)f2bf(v0.w);
      a[4] = (short)f2bf(v1.x); a[5] = (short)f2bf(v1.y);
      a[6] = (short)f2bf(v1.z); a[7] = (short)f2bf(v1.w);
#pragma unroll
      for (int g = 0; g < 4; ++g) {
        short8 b = *(const short8*)(wblk + (size_t)(g * 16 + kc) * 512 + wl);
        acc[g] = __builtin_amdgcn_mfma_f32_16x16x32_bf16(a, b, acc[g], 0, 0, 0);
      }
    }
    if (t > 0) {
      int* fl = fl_dir + (((size_t)(t - 1) << 5) + (lane & 31)) * 32 + wid * 8;
      int vv = 1;
      while (true) {
        if (lane < 32)
          vv = __hip_atomic_load(fl, __ATOMIC_RELAXED, __HIP_MEMORY_SCOPE_AGENT);
        if (__ballot(vv > 0) == ~0ull) break;
        __builtin_amdgcn_s_sleep(1);
      }
      asm volatile("" ::: "memory");
    }
    const float* hrow;
    if (t == 0) hrow = h0 + (size_t)dir * BB * HH + (size_t)(m0 + l15) * HH + quad * 8;
    else {
      const int tp = dir ? (TT - t) : (t - 1);
      hrow = out + (size_t)tp * BB * 2 * HH + (size_t)(m0 + l15) * 2 * HH + (size_t)dir * HH + quad * 8;
    }
#pragma unroll
    for (int kc = 0; kc < 16; ++kc) {
      float4 v0 = *(const float4*)(hrow + (size_t)kc * 32);
      float4 v1 = *(const float4*)(hrow + (size_t)kc * 32 + 4);
      short8 a;
      a[0] = (short)f2bf(v0.x); a[1] = (short)f2bf(v0.y);
      a[2] = (short)f2bf(v0.z); a[3] = (short)f2bf(v0.w);
      a[4] = (short)f2bf(v1.x); a[5] = (short)f2bf(v1.y);
      a[6] = (short)f2bf(v1.z); a[7] = (short)f2bf(v1.w);
#pragma unroll
      for (int g = 0; g < 4; ++g) {
        short8 b = *(const short8*)(wblk + (size_t)(64 + g * 16 + kc) * 512 + wl);
        acc[g] = __builtin_amdgcn_mfma_f32_16x16x32_bf16(a, b, acc[g], 0, 0, 0);
      }
    }
    float hf[4];
#pragma unroll
    for (int r = 0; r < 4; ++r) {
      float gi = acc[0][r] + bs[0];
      float gf = acc[1][r] + bs[1];
      float gg = acc[2][r] + bs[2];
      float go = acc[3][r] + bs[3];
      float si = 1.f / (1.f + __expf(-gi));
      float sf = 1.f / (1.f + __expf(-gf));
      float tg = 2.f / (1.f + __expf(-2.f * gg)) - 1.f;
      float so = 1.f / (1.f + __expf(-go));
      float c  = sf * cst[r] + si * tg;
      cst[r] = c;
      float th = 2.f / (1.f + __expf(-2.f * c)) - 1.f;
      hf[r] = so * th;
    }
    float* orow = out + (size_t)tt2 * BB * 2 * HH + (size_t)dir * HH + j0 + l15;
#pragma unroll
    for (int r = 0; r < 4; ++r)
      __hip_atomic_store(&orow[(size_t)(m0 + quad * 4 + r) * 2 * HH], hf[r],
                         __ATOMIC_RELAXED, __HIP_MEMORY_SCOPE_AGENT);
    asm volatile("s_waitcnt vmcnt(0)" ::: "memory");
    if (lane == 0)
      __hip_atomic_store(fl_dir + (((size_t)t << 5) + blk) * 32 + wid * 8, 1,
                         __ATOMIC_RELAXED, __HIP_MEMORY_SCOPE_AGENT);
  }
}

extern "C" void kernel_launch(void* const* d_in, const int* in_sizes, int n_in,
                              void* d_out, int out_size, void* d_ws, size_t ws_size,
                              hipStream_t stream)
{
  (void)in_sizes; (void)n_in; (void)out_size;
  const float* x     = (const float*)d_in[0];
  const float* h0    = (const float*)d_in[1];
  const float* c0    = (const float*)d_in[2];
  const float* Wih_f = (const float*)d_in[3];
  const float* Whh_f = (const float*)d_in[4];
  const float* b_f   = (const float*)d_in[5];
  const float* Wih_b = (const float*)d_in[6];
  const float* Whh_b = (const float*)d_in[7];
  const float* b_b   = (const float*)d_in[8];
  float* out = (float*)d_out;
  char* ws = (char*)d_ws;

  const size_t NEED = WF_BYTES + XA_BYTES + FLAG_BYTES + HX_BYTES;   // 108 MB
  const bool big = ws_size >= NEED;

  unsigned short* wf = (unsigned short*)ws;
  unsigned short* xa = nullptr;
  unsigned short* hxp = nullptr;
  int* flags;
  if (big) {
    xa    = (unsigned short*)(ws + WF_BYTES);
    flags = (int*)(ws + WF_BYTES + XA_BYTES);
    hxp   = (unsigned short*)(ws + WF_BYTES + XA_BYTES + FLAG_BYTES);
  } else {
    flags = (int*)(ws + WF_BYTES);
  }

  prep_kernel<<<512, 256, 0, stream>>>(Wih_f, Whh_f, Wih_b, Whh_b, wf, flags);
  if (big) {
    xconv_kernel<<<2048, 256, 0, stream>>>(x, xa);
    lstm_persist<<<64, 256, 0, stream>>>(xa, wf, flags, h0, c0, b_f, b_b, out, hxp);
  } else {
    lstm_legacy<<<64, 256, 0, stream>>>(x, wf, flags, h0, c0, b_f, b_b, out);
  }
}